// Round 10
// baseline (208.438 us; speedup 1.0000x reference)
//
#include <hip/hip_runtime.h>
#include <hip/hip_bf16.h>
#include <math.h>

#define B_ 2
#define S_ 2048
#define E_ 1024
#define H_ 16
#define D_ 64
#define M_ (B_*S_)

typedef __attribute__((ext_vector_type(8))) short short8v;
typedef __attribute__((ext_vector_type(4))) float floatx4;

__device__ __forceinline__ short f2bf(float f) {
    union { float f; unsigned u; } x; x.f = f;
    unsigned r = (x.u + 0x7fffu + ((x.u >> 16) & 1u)) >> 16;  // RNE
    return (short)r;
}

// pack two fp32 -> two bf16 in one v_perm_b32 (round-half-up)
__device__ __forceinline__ unsigned pk_bf16(float a, float b) {
    union { float f; unsigned u; } x, y;
    x.f = a; y.f = b;
    return __builtin_amdgcn_perm(y.u + 0x8000u, x.u + 0x8000u, 0x07060302u);
}

__device__ __forceinline__ float fast_exp2(float x) {
#if __has_builtin(__builtin_amdgcn_exp2f)
    return __builtin_amdgcn_exp2f(x);
#else
    return __expf(x * 0.6931471805599453f);
#endif
}

// async global->LDS, 16B per lane; LDS dest = wave-uniform base + lane*16
__device__ __forceinline__ void gl2lds16(const void* g, void* l) {
    __builtin_amdgcn_global_load_lds(
        (const __attribute__((address_space(1))) void*)g,
        (__attribute__((address_space(3))) void*)l, 16, 0, 0);
}

// XOR-swizzled fragment offset into a 64-col bf16 LDS tile:
// logical (row, 16B-chunk cg) lives at row*64 + ((cg ^ (row&7))*8).
__device__ __forceinline__ int swz_off(int row, int cg) {
    return row*64 + (((cg ^ (row & 7)) & 7) << 3);
}

// ---------------------------------------------------------------------------
// Pre-pass (merged): bid<2048 -> x fp32->bf16 flat copy;
// bid>=2048 -> W [k][n] fp32 -> Wt [n][k] bf16 (32x32 LDS tile transpose).
// ---------------------------------------------------------------------------
__global__ __launch_bounds__(256) void prep(
    const float* __restrict__ x, short* __restrict__ xb,
    const float* __restrict__ W0, const float* __restrict__ W1,
    const float* __restrict__ W2, const float* __restrict__ W3,
    short* __restrict__ T0, short* __restrict__ T1,
    short* __restrict__ T2, short* __restrict__ T3)
{
    const int bid = blockIdx.x;
    if (bid < 2048) {
        const size_t i = ((size_t)bid*256 + threadIdx.x) * 8;
        float4 a = *(const float4*)(x + i);
        float4 b = *(const float4*)(x + i + 4);
        int4 p = { (int)pk_bf16(a.x,a.y), (int)pk_bf16(a.z,a.w),
                   (int)pk_bf16(b.x,b.y), (int)pk_bf16(b.z,b.w) };
        *(int4*)(xb + i) = p;
        return;
    }
    const int tb = bid - 2048;
    const int z = tb >> 10;
    const float* W = (z==0)?W0:(z==1)?W1:(z==2)?W2:W3;
    short*       T = (z==0)?T0:(z==1)?T1:(z==2)?T2:T3;
    __shared__ float tile[32][33];
    const int k0 = ((tb>>5)&31)*32, n0 = (tb&31)*32;
    const int r = threadIdx.x >> 5, c = threadIdx.x & 31;
    #pragma unroll
    for (int i=0;i<4;i++)
        tile[r+8*i][c] = W[(size_t)(k0+r+8*i)*E_ + n0 + c];
    __syncthreads();
    #pragma unroll
    for (int i=0;i<4;i++)
        T[(size_t)(n0+r+8*i)*E_ + k0 + c] = f2bf(tile[c][r+8*i]);
}

// ---------------------------------------------------------------------------
// Fused QKV GEMM — R8-proven (best measured 42.9us): 256m x 192n tile,
// BK=64, 8 waves (2Mx4N), 512 threads. Grid 256 = 16m x 16n -> 1 block/CU.
// 8-phase counted-vmcnt schedule (T3+T4) + setprio (T5) + XOR swizzle (T2).
// [R9's 128m/2-blocks-per-CU split regressed 42.9->78.6us: halved MFMA per
//  barrier-phase; co-resident 8-phase blocks interfere. Reverted.]
// ---------------------------------------------------------------------------
__global__ __launch_bounds__(512, 2) void qkv_gemm(
    const short* __restrict__ xb, const short* __restrict__ Wt,
    const float* __restrict__ bq, const float* __restrict__ bk, const float* __restrict__ bv,
    short* __restrict__ Qo, short* __restrict__ Ko, short* __restrict__ Vo)
{
    __shared__ __align__(16) short As[2][256*64];
    __shared__ __align__(16) short Bs[2][192*64];

    const int t = threadIdx.x;
    const int wave = t >> 6, lane = t & 63;
    const int quad = lane >> 4, l15 = lane & 15;
    const int wr = wave >> 2, wc = wave & 3;          // 2x4 wave grid

    const int bid = blockIdx.x;
    const int sw  = (bid & 7) * 32 + (bid >> 3);      // XCD chunk (256%8==0)
    const int m0  = (sw >> 4) * 256;                  // 16 m-tiles
    const int nf0 = (sw & 15) * 192;                  // 16 n-tiles of 192

    const int sr8 = lane >> 3;
    const int scs = ((lane & 7) ^ sr8) * 8;           // pre-swizzled src chunk

    const short* Ag = xb + (size_t)m0  * E_;
    const short* Bg = Wt + (size_t)nf0 * E_;

    floatx4 acc[8][3];
    #pragma unroll
    for (int i=0;i<8;i++)
        #pragma unroll
        for (int j=0;j<3;j++) acc[i][j] = (floatx4){0.f,0.f,0.f,0.f};

    auto stageA = [&](int p, int h, int kt) {
        const int rb = h*128 + wave*16;
        const short* src = Ag + (size_t)(rb + sr8)*E_ + kt*64 + scs;
        #pragma unroll
        for (int c=0;c<2;c++)
            gl2lds16(src + (size_t)c*8*E_, &As[p][(rb + c*8)*64]);
    };
    auto stageB = [&](int p, int u, int kt) {
        const int rb = u*64 + wave*8;
        gl2lds16(Bg + (size_t)(rb + sr8)*E_ + kt*64 + scs, &Bs[p][rb*64]);
    };

    short8v a[2][2], b[3][2];
    auto rdA = [&](int p, int row16, int ks) -> short8v {
        return *(const short8v*)&As[p][swz_off(wr*128 + row16*16 + l15, quad + ks*4)];
    };
    auto rdB = [&](int p, int row16, int ks) -> short8v {
        return *(const short8v*)&Bs[p][swz_off(wc*48 + row16*16 + l15, quad + ks*4)];
    };
    auto lda2 = [&](int p, int mbase) {
        #pragma unroll
        for (int j=0;j<2;j++)
            #pragma unroll
            for (int ks=0;ks<2;ks++) a[j][ks] = rdA(p, mbase+j, ks);
    };
    auto mm = [&](int mbase) {
        #pragma unroll
        for (int j=0;j<2;j++)
            #pragma unroll
            for (int nt=0;nt<3;nt++)
                #pragma unroll
                for (int ks=0;ks<2;ks++)
                    acc[mbase+j][nt] = __builtin_amdgcn_mfma_f32_16x16x32_bf16(
                        a[j][ks], b[nt][ks], acc[mbase+j][nt], 0,0,0);
    };

    auto ktile = [&](int tt, int p) {
        // ---- phase 0: all B frags + A m0-1; stage A-h0(t+1) ----
        #pragma unroll
        for (int nt=0;nt<3;nt++)
            #pragma unroll
            for (int ks=0;ks<2;ks++) b[nt][ks] = rdB(p, nt, ks);
        lda2(p, 0);
        if (tt+1 < 16) stageA(p^1, 0, tt+1);
        __builtin_amdgcn_s_barrier();
        __builtin_amdgcn_s_setprio(1);
        mm(0);
        __builtin_amdgcn_s_setprio(0);
        __builtin_amdgcn_s_barrier();
        // ---- phase 1: A m2-3; stage A-h1(t+1) ----
        lda2(p, 2);
        if (tt+1 < 16) stageA(p^1, 1, tt+1);
        __builtin_amdgcn_s_barrier();
        __builtin_amdgcn_s_setprio(1);
        mm(2);
        __builtin_amdgcn_s_setprio(0);
        __builtin_amdgcn_s_barrier();
        // ---- phase 2: A m4-5; stage B-u0,u1(t+2) ----
        lda2(p, 4);
        if (tt+2 < 16) { stageB(p, 0, tt+2); stageB(p, 1, tt+2); }
        __builtin_amdgcn_s_barrier();
        __builtin_amdgcn_s_setprio(1);
        mm(4);
        __builtin_amdgcn_s_setprio(0);
        __builtin_amdgcn_s_barrier();
        // ---- phase 3: A m6-7; stage B-u2(t+2) ----
        lda2(p, 6);
        if (tt+2 < 16) stageB(p, 2, tt+2);
        __builtin_amdgcn_s_barrier();
        __builtin_amdgcn_s_setprio(1);
        mm(6);
        __builtin_amdgcn_s_setprio(0);
        if (tt+2 < 16)      asm volatile("s_waitcnt vmcnt(3)" ::: "memory");
        else if (tt+1 < 16) asm volatile("s_waitcnt vmcnt(0)" ::: "memory");
        __builtin_amdgcn_s_barrier();
    };

    // prologue: A(0), B(0), B(1); A(1) is staged by tile0 per the schedule.
    stageA(0,0,0); stageA(0,1,0);
    stageB(0,0,0); stageB(0,1,0); stageB(0,2,0);
    stageB(1,0,1); stageB(1,1,1); stageB(1,2,1);
    asm volatile("s_waitcnt vmcnt(3)" ::: "memory");   // A(0),B(0) landed
    __builtin_amdgcn_s_barrier();

    #pragma unroll 1
    for (int tb = 0; tb < 16; tb += 2) {
        ktile(tb,   0);
        ktile(tb+1, 1);
    }

    // ---- epilogue: per-FRAGMENT z select + scatter ----
    #pragma unroll
    for (int nt=0;nt<3;nt++) {
        const int nwg = nf0 + wc*48 + nt*16 + l15;     // global fused col
        const int zf  = nwg >> 10;                     // uniform per frag
        const float* bbf = (zf==0) ? bq : (zf==1) ? bk : bv;
        short* outf      = (zf==0) ? Qo : (zf==1) ? Ko : Vo;
        const float scf  = (zf==0) ? 0.18033688011112042f : 1.0f;
        const int nl = nwg & 1023;
        const float bias = bbf[nl];
        const int h = nl >> 6, d = nl & 63;
        #pragma unroll
        for (int mt=0;mt<8;mt++) {
            #pragma unroll
            for (int r=0;r<4;r++) {
                const int m = m0 + wr*128 + mt*16 + quad*4 + r;
                const int b2 = m >> 11, s = m & (S_-1);
                const int bh = (b2<<4) + h;
                const float v = (acc[mt][nt][r] + bias) * scf;
                if (zf == 0) {
                    outf[((size_t)bh*S_ + s)*D_ + d] = f2bf(v);
                } else if (zf == 1) {
                    const int ts = s >> 6, kk = s & 63;
                    const int c = kk*8 + ((d>>3) ^ ((kk>>2)&7));
                    outf[((size_t)bh*32 + ts)*4096 + c*8 + (d&7)] = f2bf(v);
                } else {
                    const int ts = s >> 6, sk = s & 63;
                    const int c = d*8 + ((sk>>3) ^ (d&7));
                    outf[((size_t)bh*32 + ts)*4096 + c*8 + (sk&7)] = f2bf(v);
                }
            }
        }
    }
}

// ---------------------------------------------------------------------------
// Causal flash attention, LDS-staged K/V, T5 setprio. (R8 structure)
// 64-row q-blocks; grid (S/64, B*H): qtile in x, bh in y -> 32 consecutive
// linear block IDs share one bh, so each XCD's L2 serves ~4 q-tiles from
// the SAME 512KB K/V panel (x=bh ordering round-robined distinct panels).
// LDS 41KB -> 3 blocks/CU. Each of 4 waves owns ONE 16-row q-tile. Psl
// single-buffered, wave-private. Mask only on diagonal tile. Longest first.
// ---------------------------------------------------------------------------
__global__ __launch_bounds__(256, 3) void attn_kernel(
    const short* __restrict__ Q, const short* __restrict__ K, const short* __restrict__ V,
    short* __restrict__ AO)
{
    const int bh = blockIdx.y;
    const int qb = (gridDim.x - 1 - blockIdx.x) * 64;   // longest first
    const int t = threadIdx.x;
    const int wave = t >> 6, lane = t & 63;
    const int quad = lane >> 4, l15 = lane & 15;

    const short* Qp = Q + (size_t)bh * (S_*D_);
    const short* Kp = K + (size_t)bh * (S_*D_);
    const short* Vp = V + (size_t)bh * (S_*D_);

    __shared__ __align__(16) short KVs[2][8192];   // [parity][K 8KB | V 8KB]
    __shared__ __align__(16) short Psl[4][16*72];  // [wave] single-buf, private

    const int qA = qb + wave*16;
    const short* qa = Qp + (size_t)(qA + l15)*D_ + quad*8;
    const short8v qA0 = *(const short8v*)qa, qA1 = *(const short8v*)(qa + 32);
    const int qrbA = qA + quad*4;

    floatx4 oA[4];
    #pragma unroll
    for (int i=0;i<4;i++) oA[i] = (floatx4){0,0,0,0};
    float tsA[4] = {0,0,0,0};

    const int L = (qb >> 6) + 1;     // #K-tiles (may be odd)
    const int swz = l15 & 7;

    auto stage = [&](int kt, int p) {
        const short* src = ((wave < 2) ? Kp : Vp) + (size_t)kt*4096 + (wave&1)*2048 + lane*8;
        short* dst = &KVs[p][((wave < 2) ? 0 : 4096) + (wave&1)*2048];
        #pragma unroll
        for (int c=0;c<4;c++)
            gl2lds16(src + c*512, dst + c*512);
    };
    auto qk1 = [&](const short* KL, floatx4 (&sA)[4]) {
        __builtin_amdgcn_s_setprio(1);
        #pragma unroll
        for (int h=0; h<4; h++) {
            const int rowc = (4*l15 + h)*8;
            short8v b0 = *(const short8v*)(KL + (rowc + (quad       ^ swz))*8);
            short8v b1 = *(const short8v*)(KL + (rowc + ((4 + quad) ^ swz))*8);
            sA[h] = (floatx4){0.f,0.f,0.f,0.f};
            sA[h] = __builtin_amdgcn_mfma_f32_16x16x32_bf16(qA0, b0, sA[h], 0,0,0);
            sA[h] = __builtin_amdgcn_mfma_f32_16x16x32_bf16(qA1, b1, sA[h], 0,0,0);
        }
        __builtin_amdgcn_s_setprio(0);
    };
    auto soft_u = [&](floatx4 (&s)[4], float* ts, short* pw, int qrb, int k0, bool masked) {
        const int kk = k0 + 4*l15;
        #pragma unroll
        for (int r=0; r<4; r++) {
            float p[4];
            if (masked) {
                const int qr = qrb + r;
                #pragma unroll
                for (int h=0; h<4; h++) {
                    const float e = fast_exp2(s[h][r]);
                    p[h] = (kk + h > qr) ? 0.f : e;
                }
            } else {
                #pragma unroll
                for (int h=0; h<4; h++) p[h] = fast_exp2(s[h][r]);
            }
            ts[r] += (p[0] + p[1]) + (p[2] + p[3]);
            int2 pkv = { (int)pk_bf16(p[0], p[1]), (int)pk_bf16(p[2], p[3]) };
            *(int2*)(pw + (quad*4 + r)*72 + l15*4) = pkv;
        }
    };
    short8v vr[4][2];
    auto loadv = [&](const short* VL) {
        #pragma unroll
        for (int dt=0; dt<4; dt++) {
            const int rowc = (dt*16 + l15)*8;
            vr[dt][0] = *(const short8v*)(VL + (rowc + (quad       ^ swz))*8);
            vr[dt][1] = *(const short8v*)(VL + (rowc + ((4 + quad) ^ swz))*8);
        }
    };
    auto pv = [&](const short* pw, floatx4 (&o)[4]) {
        const short8v pf0 = *(const short8v*)(pw + l15*72 + quad*8);
        const short8v pf1 = *(const short8v*)(pw + l15*72 + 32 + quad*8);
        __builtin_amdgcn_s_setprio(1);
        #pragma unroll
        for (int dt=0; dt<4; dt++) {
            o[dt] = __builtin_amdgcn_mfma_f32_16x16x32_bf16(pf0, vr[dt][0], o[dt], 0,0,0);
            o[dt] = __builtin_amdgcn_mfma_f32_16x16x32_bf16(pf1, vr[dt][1], o[dt], 0,0,0);
        }
        __builtin_amdgcn_s_setprio(0);
    };

    // ---- prologue: tile 0 ----
    stage(0, 0);
    __syncthreads();
    if (L > 1) stage(1, 1);
    {
        floatx4 sA[4];
        qk1(&KVs[0][0], sA);
        loadv(&KVs[0][4096]);
        soft_u(sA, tsA, &Psl[wave][0], qrbA, 0, L == 1);
    }

    for (int kt = 1; kt < L; kt++) {
        const int p = kt & 1;
        __syncthreads();
        if (kt + 1 < L) stage(kt + 1, p ^ 1);
        floatx4 sA[4];
        qk1(&KVs[p][0], sA);
        pv(&Psl[wave][0], oA);          // reads P(kt-1); DS in-order per wave
        loadv(&KVs[p][4096]);
        soft_u(sA, tsA, &Psl[wave][0], qrbA, kt << 6, kt == L - 1);
    }

    pv(&Psl[wave][0], oA);

    float lA[4];
    #pragma unroll
    for (int r=0; r<4; r++) {
        float a = tsA[r];
        #pragma unroll
        for (int off=1; off<16; off<<=1) a += __shfl_xor(a, off);
        lA[r] = a;
    }

    const int b = bh >> 4, h = bh & 15;
    #pragma unroll
    for (int dt=0; dt<4; dt++) {
        #pragma unroll
        for (int r=0; r<4; r++) {
            const int d = dt*16 + l15;
            const int sA_ = qA + quad*4 + r;
            AO[((size_t)(b*S_ + sA_)*H_ + h)*D_ + d] = f2bf(oA[dt][r] / lA[r]);
        }
    }
}

// ---------------------------------------------------------------------------
// Output GEMM: 128m x 64n tiles (512 blocks = 2/CU for barrier overlap),
// BK=64, XOR-swizzled LDS, XCD swizzle m = lin&31.
// ---------------------------------------------------------------------------
__global__ __launch_bounds__(256) void out_gemm(
    const short* __restrict__ A, const short* __restrict__ Wto,
    const float* __restrict__ bo, float* __restrict__ out)
{
    __shared__ __align__(16) short As[128*64];
    __shared__ __align__(16) short Bs[64*64];

    const int t = threadIdx.x;
    const int wave = t >> 6, lane = t & 63;
    const int quad = lane >> 4, l15 = lane & 15;
    const int lin = blockIdx.x;
    const int m0 = (lin & 31) * 128;
    const int n0 = (lin >> 5) * 64;
    const int sr8 = lane >> 3;
    const int scs = ((lane & 7) ^ sr8) * 8;

    floatx4 acc[2][4];
    #pragma unroll
    for (int i=0;i<2;i++)
        #pragma unroll
        for (int j=0;j<4;j++) acc[i][j] = (floatx4){0.f,0.f,0.f,0.f};

    for (int k0 = 0; k0 < E_; k0 += 64) {
        #pragma unroll
        for (int c=0;c<4;c++) {
            const int rb = wave*32 + c*8;
            gl2lds16(A + (size_t)(m0+rb+sr8)*E_ + k0 + scs, &As[rb*64]);
        }
        #pragma unroll
        for (int c=0;c<2;c++) {
            const int rb = wave*16 + c*8;
            gl2lds16(Wto + (size_t)(n0+rb+sr8)*E_ + k0 + scs, &Bs[rb*64]);
        }
        __syncthreads();
        #pragma unroll
        for (int ks=0; ks<2; ks++) {
            const int cg = quad + ks*4;
            short8v a[2], b[4];
            #pragma unroll
            for (int mt=0;mt<2;mt++) a[mt] = *(const short8v*)&As[swz_off(wave*32+mt*16+l15, cg)];
            #pragma unroll
            for (int nt=0;nt<4;nt++) b[nt] = *(const short8v*)&Bs[swz_off(nt*16+l15, cg)];
            #pragma unroll
            for (int mt=0;mt<2;mt++)
                #pragma unroll
                for (int nt=0;nt<4;nt++)
                    acc[mt][nt] = __builtin_amdgcn_mfma_f32_16x16x32_bf16(a[mt], b[nt], acc[mt][nt], 0,0,0);
        }
        __syncthreads();
    }

    #pragma unroll
    for (int nt=0;nt<4;nt++) {
        const int n = n0 + nt*16 + l15;
        const float bias = bo[n];
        #pragma unroll
        for (int mt=0;mt<2;mt++) {
            #pragma unroll
            for (int r=0;r<4;r++) {
                const int m = m0 + wave*32 + mt*16 + quad*4 + r;
                out[(size_t)m*E_ + n] = acc[mt][nt][r] + bias;
            }
        }
    }
}

extern "C" void kernel_launch(void* const* d_in, const int* in_sizes, int n_in,
                              void* d_out, int out_size, void* d_ws, size_t ws_size,
                              hipStream_t stream)
{
    const float* x  = (const float*)d_in[0];
    const float* Wq = (const float*)d_in[1];
    const float* bq = (const float*)d_in[2];
    const float* Wk = (const float*)d_in[3];
    const float* bk = (const float*)d_in[4];
    const float* Wv = (const float*)d_in[5];
    const float* bv = (const float*)d_in[6];
    const float* Wo = (const float*)d_in[7];
    const float* bo = (const float*)d_in[8];

    short* xb  = (short*)d_ws;                   // bf16 [4096,1024]
    short* Tq  = xb  + (size_t)M_ * E_;          // bf16 Wq^T [n][k]; Tq|Tk|Tv fused
    short* Tk  = Tq  + (size_t)E_ * E_;
    short* Tv  = Tk  + (size_t)E_ * E_;
    short* To  = Tv  + (size_t)E_ * E_;
    short* Qw  = To  + (size_t)E_ * E_;          // bf16 [B,H,S,D] (exp2-scaled)
    short* Kw  = Qw  + (size_t)M_ * E_;          // bf16 tiled-swizzled K
    short* Vw  = Kw  + (size_t)M_ * E_;          // bf16 tiled-swizzled V
    short* AOw = Vw  + (size_t)M_ * E_;          // bf16 [B,S,H,D]

    dim3 blk(256);
    prep<<<dim3(2048 + 4096), blk, 0, stream>>>(x, xb, Wq, Wk, Wv, Wo, Tq, Tk, Tv, To);
    qkv_gemm<<<dim3(256), dim3(512), 0, stream>>>(xb, Tq, bq, bk, bv, Qw, Kw, Vw);
    attn_kernel<<<dim3(S_/64, B_*H_), blk, 0, stream>>>(Qw, Kw, Vw, AOw);
    out_gemm<<<dim3(512), blk, 0, stream>>>(AOw, To, bo, (float*)d_out);
}

// Round 11
// 176.246 us; speedup vs baseline: 1.1827x; 1.1827x over previous
//
#include <hip/hip_runtime.h>
#include <hip/hip_bf16.h>
#include <math.h>

#define B_ 2
#define S_ 2048
#define E_ 1024
#define H_ 16
#define D_ 64
#define M_ (B_*S_)

typedef __attribute__((ext_vector_type(8))) short short8v;
typedef __attribute__((ext_vector_type(4))) float floatx4;

__device__ __forceinline__ short f2bf(float f) {
    union { float f; unsigned u; } x; x.f = f;
    unsigned r = (x.u + 0x7fffu + ((x.u >> 16) & 1u)) >> 16;  // RNE
    return (short)r;
}

// pack two fp32 -> two bf16 in one v_perm_b32 (round-half-up)
__device__ __forceinline__ unsigned pk_bf16(float a, float b) {
    union { float f; unsigned u; } x, y;
    x.f = a; y.f = b;
    return __builtin_amdgcn_perm(y.u + 0x8000u, x.u + 0x8000u, 0x07060302u);
}

__device__ __forceinline__ float fast_exp2(float x) {
#if __has_builtin(__builtin_amdgcn_exp2f)
    return __builtin_amdgcn_exp2f(x);
#else
    return __expf(x * 0.6931471805599453f);
#endif
}

// async global->LDS, 16B per lane; LDS dest = wave-uniform base + lane*16
__device__ __forceinline__ void gl2lds16(const void* g, void* l) {
    __builtin_amdgcn_global_load_lds(
        (const __attribute__((address_space(1))) void*)g,
        (__attribute__((address_space(3))) void*)l, 16, 0, 0);
}

// XOR-swizzled fragment offset into a 64-col bf16 LDS tile:
// logical (row, 16B-chunk cg) lives at row*64 + ((cg ^ (row&7))*8).
__device__ __forceinline__ int swz_off(int row, int cg) {
    return row*64 + (((cg ^ (row & 7)) & 7) << 3);
}

// ---------------------------------------------------------------------------
// Pre-pass (merged): bid<2048 -> x fp32->bf16 flat copy;
// bid>=2048 -> W [k][n] fp32 -> Wt [n][k] bf16 (32x32 LDS tile transpose).
// ---------------------------------------------------------------------------
__global__ __launch_bounds__(256) void prep(
    const float* __restrict__ x, short* __restrict__ xb,
    const float* __restrict__ W0, const float* __restrict__ W1,
    const float* __restrict__ W2, const float* __restrict__ W3,
    short* __restrict__ T0, short* __restrict__ T1,
    short* __restrict__ T2, short* __restrict__ T3)
{
    const int bid = blockIdx.x;
    if (bid < 2048) {
        const size_t i = ((size_t)bid*256 + threadIdx.x) * 8;
        float4 a = *(const float4*)(x + i);
        float4 b = *(const float4*)(x + i + 4);
        int4 p = { (int)pk_bf16(a.x,a.y), (int)pk_bf16(a.z,a.w),
                   (int)pk_bf16(b.x,b.y), (int)pk_bf16(b.z,b.w) };
        *(int4*)(xb + i) = p;
        return;
    }
    const int tb = bid - 2048;
    const int z = tb >> 10;
    const float* W = (z==0)?W0:(z==1)?W1:(z==2)?W2:W3;
    short*       T = (z==0)?T0:(z==1)?T1:(z==2)?T2:T3;
    __shared__ float tile[32][33];
    const int k0 = ((tb>>5)&31)*32, n0 = (tb&31)*32;
    const int r = threadIdx.x >> 5, c = threadIdx.x & 31;
    #pragma unroll
    for (int i=0;i<4;i++)
        tile[r+8*i][c] = W[(size_t)(k0+r+8*i)*E_ + n0 + c];
    __syncthreads();
    #pragma unroll
    for (int i=0;i<4;i++)
        T[(size_t)(n0+r+8*i)*E_ + k0 + c] = f2bf(tile[c][r+8*i]);
}

// ---------------------------------------------------------------------------
// Fused QKV GEMM — R8-proven (best measured 42.9us): 256m x 192n tile,
// BK=64, 8 waves (2Mx4N), 512 threads. Grid 256 = 16m x 16n -> 1 block/CU.
// 8-phase counted-vmcnt schedule (T3+T4) + setprio (T5) + XOR swizzle (T2).
// [R9's 128m/2-blocks-per-CU split regressed 42.9->78.6us. Reverted.]
// ---------------------------------------------------------------------------
__global__ __launch_bounds__(512, 2) void qkv_gemm(
    const short* __restrict__ xb, const short* __restrict__ Wt,
    const float* __restrict__ bq, const float* __restrict__ bk, const float* __restrict__ bv,
    short* __restrict__ Qo, short* __restrict__ Ko, short* __restrict__ Vo)
{
    __shared__ __align__(16) short As[2][256*64];
    __shared__ __align__(16) short Bs[2][192*64];

    const int t = threadIdx.x;
    const int wave = t >> 6, lane = t & 63;
    const int quad = lane >> 4, l15 = lane & 15;
    const int wr = wave >> 2, wc = wave & 3;          // 2x4 wave grid

    const int bid = blockIdx.x;
    const int sw  = (bid & 7) * 32 + (bid >> 3);      // XCD chunk (256%8==0)
    const int m0  = (sw >> 4) * 256;                  // 16 m-tiles
    const int nf0 = (sw & 15) * 192;                  // 16 n-tiles of 192

    const int sr8 = lane >> 3;
    const int scs = ((lane & 7) ^ sr8) * 8;           // pre-swizzled src chunk

    const short* Ag = xb + (size_t)m0  * E_;
    const short* Bg = Wt + (size_t)nf0 * E_;

    floatx4 acc[8][3];
    #pragma unroll
    for (int i=0;i<8;i++)
        #pragma unroll
        for (int j=0;j<3;j++) acc[i][j] = (floatx4){0.f,0.f,0.f,0.f};

    auto stageA = [&](int p, int h, int kt) {
        const int rb = h*128 + wave*16;
        const short* src = Ag + (size_t)(rb + sr8)*E_ + kt*64 + scs;
        #pragma unroll
        for (int c=0;c<2;c++)
            gl2lds16(src + (size_t)c*8*E_, &As[p][(rb + c*8)*64]);
    };
    auto stageB = [&](int p, int u, int kt) {
        const int rb = u*64 + wave*8;
        gl2lds16(Bg + (size_t)(rb + sr8)*E_ + kt*64 + scs, &Bs[p][rb*64]);
    };

    short8v a[2][2], b[3][2];
    auto rdA = [&](int p, int row16, int ks) -> short8v {
        return *(const short8v*)&As[p][swz_off(wr*128 + row16*16 + l15, quad + ks*4)];
    };
    auto rdB = [&](int p, int row16, int ks) -> short8v {
        return *(const short8v*)&Bs[p][swz_off(wc*48 + row16*16 + l15, quad + ks*4)];
    };
    auto lda2 = [&](int p, int mbase) {
        #pragma unroll
        for (int j=0;j<2;j++)
            #pragma unroll
            for (int ks=0;ks<2;ks++) a[j][ks] = rdA(p, mbase+j, ks);
    };
    auto mm = [&](int mbase) {
        #pragma unroll
        for (int j=0;j<2;j++)
            #pragma unroll
            for (int nt=0;nt<3;nt++)
                #pragma unroll
                for (int ks=0;ks<2;ks++)
                    acc[mbase+j][nt] = __builtin_amdgcn_mfma_f32_16x16x32_bf16(
                        a[j][ks], b[nt][ks], acc[mbase+j][nt], 0,0,0);
    };

    auto ktile = [&](int tt, int p) {
        // ---- phase 0: all B frags + A m0-1; stage A-h0(t+1) ----
        #pragma unroll
        for (int nt=0;nt<3;nt++)
            #pragma unroll
            for (int ks=0;ks<2;ks++) b[nt][ks] = rdB(p, nt, ks);
        lda2(p, 0);
        if (tt+1 < 16) stageA(p^1, 0, tt+1);
        __builtin_amdgcn_s_barrier();
        __builtin_amdgcn_s_setprio(1);
        mm(0);
        __builtin_amdgcn_s_setprio(0);
        __builtin_amdgcn_s_barrier();
        // ---- phase 1: A m2-3; stage A-h1(t+1) ----
        lda2(p, 2);
        if (tt+1 < 16) stageA(p^1, 1, tt+1);
        __builtin_amdgcn_s_barrier();
        __builtin_amdgcn_s_setprio(1);
        mm(2);
        __builtin_amdgcn_s_setprio(0);
        __builtin_amdgcn_s_barrier();
        // ---- phase 2: A m4-5; stage B-u0,u1(t+2) ----
        lda2(p, 4);
        if (tt+2 < 16) { stageB(p, 0, tt+2); stageB(p, 1, tt+2); }
        __builtin_amdgcn_s_barrier();
        __builtin_amdgcn_s_setprio(1);
        mm(4);
        __builtin_amdgcn_s_setprio(0);
        __builtin_amdgcn_s_barrier();
        // ---- phase 3: A m6-7; stage B-u2(t+2) ----
        lda2(p, 6);
        if (tt+2 < 16) stageB(p, 2, tt+2);
        __builtin_amdgcn_s_barrier();
        __builtin_amdgcn_s_setprio(1);
        mm(6);
        __builtin_amdgcn_s_setprio(0);
        if (tt+2 < 16)      asm volatile("s_waitcnt vmcnt(3)" ::: "memory");
        else if (tt+1 < 16) asm volatile("s_waitcnt vmcnt(0)" ::: "memory");
        __builtin_amdgcn_s_barrier();
    };

    // prologue: A(0), B(0), B(1); A(1) is staged by tile0 per the schedule.
    stageA(0,0,0); stageA(0,1,0);
    stageB(0,0,0); stageB(0,1,0); stageB(0,2,0);
    stageB(1,0,1); stageB(1,1,1); stageB(1,2,1);
    asm volatile("s_waitcnt vmcnt(3)" ::: "memory");   // A(0),B(0) landed
    __builtin_amdgcn_s_barrier();

    #pragma unroll 1
    for (int tb = 0; tb < 16; tb += 2) {
        ktile(tb,   0);
        ktile(tb+1, 1);
    }

    // ---- epilogue: per-FRAGMENT z select + scatter ----
    #pragma unroll
    for (int nt=0;nt<3;nt++) {
        const int nwg = nf0 + wc*48 + nt*16 + l15;     // global fused col
        const int zf  = nwg >> 10;                     // uniform per frag
        const float* bbf = (zf==0) ? bq : (zf==1) ? bk : bv;
        short* outf      = (zf==0) ? Qo : (zf==1) ? Ko : Vo;
        const float scf  = (zf==0) ? 0.18033688011112042f : 1.0f;
        const int nl = nwg & 1023;
        const float bias = bbf[nl];
        const int h = nl >> 6, d = nl & 63;
        #pragma unroll
        for (int mt=0;mt<8;mt++) {
            #pragma unroll
            for (int r=0;r<4;r++) {
                const int m = m0 + wr*128 + mt*16 + quad*4 + r;
                const int b2 = m >> 11, s = m & (S_-1);
                const int bh = (b2<<4) + h;
                const float v = (acc[mt][nt][r] + bias) * scf;
                if (zf == 0) {
                    outf[((size_t)bh*S_ + s)*D_ + d] = f2bf(v);
                } else if (zf == 1) {
                    const int ts = s >> 6, kk = s & 63;
                    const int c = kk*8 + ((d>>3) ^ ((kk>>2)&7));
                    outf[((size_t)bh*32 + ts)*4096 + c*8 + (d&7)] = f2bf(v);
                } else {
                    const int ts = s >> 6, sk = s & 63;
                    const int c = d*8 + ((sk>>3) ^ (d&7));
                    outf[((size_t)bh*32 + ts)*4096 + c*8 + (sk&7)] = f2bf(v);
                }
            }
        }
    }
}

// ---------------------------------------------------------------------------
// Causal flash attention, LDS-staged K/V, T5 setprio. (R8-proven, best)
// 64-row q-blocks -> grid (B*H, S/64) = 1024 blocks; bh-major linear order
// (qtile-major R10 variant thrashed L2: FETCH 12.4->62.5MB. Reverted.)
// LDS 41KB -> 3 blocks/CU. Each of 4 waves owns ONE 16-row q-tile. Psl
// single-buffered, wave-private. Mask only on diagonal tile. Longest first.
// ---------------------------------------------------------------------------
__global__ __launch_bounds__(256, 3) void attn_kernel(
    const short* __restrict__ Q, const short* __restrict__ K, const short* __restrict__ V,
    short* __restrict__ AO)
{
    const int bh = blockIdx.x;
    const int qb = (gridDim.y - 1 - blockIdx.y) * 64;   // longest first
    const int t = threadIdx.x;
    const int wave = t >> 6, lane = t & 63;
    const int quad = lane >> 4, l15 = lane & 15;

    const short* Qp = Q + (size_t)bh * (S_*D_);
    const short* Kp = K + (size_t)bh * (S_*D_);
    const short* Vp = V + (size_t)bh * (S_*D_);

    __shared__ __align__(16) short KVs[2][8192];   // [parity][K 8KB | V 8KB]
    __shared__ __align__(16) short Psl[4][16*72];  // [wave] single-buf, private

    const int qA = qb + wave*16;
    const short* qa = Qp + (size_t)(qA + l15)*D_ + quad*8;
    const short8v qA0 = *(const short8v*)qa, qA1 = *(const short8v*)(qa + 32);
    const int qrbA = qA + quad*4;

    floatx4 oA[4];
    #pragma unroll
    for (int i=0;i<4;i++) oA[i] = (floatx4){0,0,0,0};
    float tsA[4] = {0,0,0,0};

    const int L = (qb >> 6) + 1;     // #K-tiles (may be odd)
    const int swz = l15 & 7;

    auto stage = [&](int kt, int p) {
        const short* src = ((wave < 2) ? Kp : Vp) + (size_t)kt*4096 + (wave&1)*2048 + lane*8;
        short* dst = &KVs[p][((wave < 2) ? 0 : 4096) + (wave&1)*2048];
        #pragma unroll
        for (int c=0;c<4;c++)
            gl2lds16(src + c*512, dst + c*512);
    };
    auto qk1 = [&](const short* KL, floatx4 (&sA)[4]) {
        __builtin_amdgcn_s_setprio(1);
        #pragma unroll
        for (int h=0; h<4; h++) {
            const int rowc = (4*l15 + h)*8;
            short8v b0 = *(const short8v*)(KL + (rowc + (quad       ^ swz))*8);
            short8v b1 = *(const short8v*)(KL + (rowc + ((4 + quad) ^ swz))*8);
            sA[h] = (floatx4){0.f,0.f,0.f,0.f};
            sA[h] = __builtin_amdgcn_mfma_f32_16x16x32_bf16(qA0, b0, sA[h], 0,0,0);
            sA[h] = __builtin_amdgcn_mfma_f32_16x16x32_bf16(qA1, b1, sA[h], 0,0,0);
        }
        __builtin_amdgcn_s_setprio(0);
    };
    auto soft_u = [&](floatx4 (&s)[4], float* ts, short* pw, int qrb, int k0, bool masked) {
        const int kk = k0 + 4*l15;
        #pragma unroll
        for (int r=0; r<4; r++) {
            float p[4];
            if (masked) {
                const int qr = qrb + r;
                #pragma unroll
                for (int h=0; h<4; h++) {
                    const float e = fast_exp2(s[h][r]);
                    p[h] = (kk + h > qr) ? 0.f : e;
                }
            } else {
                #pragma unroll
                for (int h=0; h<4; h++) p[h] = fast_exp2(s[h][r]);
            }
            ts[r] += (p[0] + p[1]) + (p[2] + p[3]);
            int2 pkv = { (int)pk_bf16(p[0], p[1]), (int)pk_bf16(p[2], p[3]) };
            *(int2*)(pw + (quad*4 + r)*72 + l15*4) = pkv;
        }
    };
    short8v vr[4][2];
    auto loadv = [&](const short* VL) {
        #pragma unroll
        for (int dt=0; dt<4; dt++) {
            const int rowc = (dt*16 + l15)*8;
            vr[dt][0] = *(const short8v*)(VL + (rowc + (quad       ^ swz))*8);
            vr[dt][1] = *(const short8v*)(VL + (rowc + ((4 + quad) ^ swz))*8);
        }
    };
    auto pv = [&](const short* pw, floatx4 (&o)[4]) {
        const short8v pf0 = *(const short8v*)(pw + l15*72 + quad*8);
        const short8v pf1 = *(const short8v*)(pw + l15*72 + 32 + quad*8);
        __builtin_amdgcn_s_setprio(1);
        #pragma unroll
        for (int dt=0; dt<4; dt++) {
            o[dt] = __builtin_amdgcn_mfma_f32_16x16x32_bf16(pf0, vr[dt][0], o[dt], 0,0,0);
            o[dt] = __builtin_amdgcn_mfma_f32_16x16x32_bf16(pf1, vr[dt][1], o[dt], 0,0,0);
        }
        __builtin_amdgcn_s_setprio(0);
    };

    // ---- prologue: tile 0 ----
    stage(0, 0);
    __syncthreads();
    if (L > 1) stage(1, 1);
    {
        floatx4 sA[4];
        qk1(&KVs[0][0], sA);
        loadv(&KVs[0][4096]);
        soft_u(sA, tsA, &Psl[wave][0], qrbA, 0, L == 1);
    }

    for (int kt = 1; kt < L; kt++) {
        const int p = kt & 1;
        __syncthreads();
        if (kt + 1 < L) stage(kt + 1, p ^ 1);
        floatx4 sA[4];
        qk1(&KVs[p][0], sA);
        pv(&Psl[wave][0], oA);          // reads P(kt-1); DS in-order per wave
        loadv(&KVs[p][4096]);
        soft_u(sA, tsA, &Psl[wave][0], qrbA, kt << 6, kt == L - 1);
    }

    pv(&Psl[wave][0], oA);

    float lA[4];
    #pragma unroll
    for (int r=0; r<4; r++) {
        float a = tsA[r];
        #pragma unroll
        for (int off=1; off<16; off<<=1) a += __shfl_xor(a, off);
        lA[r] = a;
    }

    const int b = bh >> 4, h = bh & 15;
    #pragma unroll
    for (int dt=0; dt<4; dt++) {
        #pragma unroll
        for (int r=0; r<4; r++) {
            const int d = dt*16 + l15;
            const int sA_ = qA + quad*4 + r;
            AO[((size_t)(b*S_ + sA_)*H_ + h)*D_ + d] = f2bf(oA[dt][r] / lA[r]);
        }
    }
}

// ---------------------------------------------------------------------------
// Output GEMM: 128m x 64n tiles (512 blocks = 2/CU for barrier overlap),
// BK=64, XOR-swizzled LDS, XCD swizzle m = lin&31.
// ---------------------------------------------------------------------------
__global__ __launch_bounds__(256) void out_gemm(
    const short* __restrict__ A, const short* __restrict__ Wto,
    const float* __restrict__ bo, float* __restrict__ out)
{
    __shared__ __align__(16) short As[128*64];
    __shared__ __align__(16) short Bs[64*64];

    const int t = threadIdx.x;
    const int wave = t >> 6, lane = t & 63;
    const int quad = lane >> 4, l15 = lane & 15;
    const int lin = blockIdx.x;
    const int m0 = (lin & 31) * 128;
    const int n0 = (lin >> 5) * 64;
    const int sr8 = lane >> 3;
    const int scs = ((lane & 7) ^ sr8) * 8;

    floatx4 acc[2][4];
    #pragma unroll
    for (int i=0;i<2;i++)
        #pragma unroll
        for (int j=0;j<4;j++) acc[i][j] = (floatx4){0.f,0.f,0.f,0.f};

    for (int k0 = 0; k0 < E_; k0 += 64) {
        #pragma unroll
        for (int c=0;c<4;c++) {
            const int rb = wave*32 + c*8;
            gl2lds16(A + (size_t)(m0+rb+sr8)*E_ + k0 + scs, &As[rb*64]);
        }
        #pragma unroll
        for (int c=0;c<2;c++) {
            const int rb = wave*16 + c*8;
            gl2lds16(Wto + (size_t)(n0+rb+sr8)*E_ + k0 + scs, &Bs[rb*64]);
        }
        __syncthreads();
        #pragma unroll
        for (int ks=0; ks<2; ks++) {
            const int cg = quad + ks*4;
            short8v a[2], b[4];
            #pragma unroll
            for (int mt=0;mt<2;mt++) a[mt] = *(const short8v*)&As[swz_off(wave*32+mt*16+l15, cg)];
            #pragma unroll
            for (int nt=0;nt<4;nt++) b[nt] = *(const short8v*)&Bs[swz_off(nt*16+l15, cg)];
            #pragma unroll
            for (int mt=0;mt<2;mt++)
                #pragma unroll
                for (int nt=0;nt<4;nt++)
                    acc[mt][nt] = __builtin_amdgcn_mfma_f32_16x16x32_bf16(a[mt], b[nt], acc[mt][nt], 0,0,0);
        }
        __syncthreads();
    }

    #pragma unroll
    for (int nt=0;nt<4;nt++) {
        const int n = n0 + nt*16 + l15;
        const float bias = bo[n];
        #pragma unroll
        for (int mt=0;mt<2;mt++) {
            #pragma unroll
            for (int r=0;r<4;r++) {
                const int m = m0 + wave*32 + mt*16 + quad*4 + r;
                out[(size_t)m*E_ + n] = acc[mt][nt][r] + bias;
            }
        }
    }
}

extern "C" void kernel_launch(void* const* d_in, const int* in_sizes, int n_in,
                              void* d_out, int out_size, void* d_ws, size_t ws_size,
                              hipStream_t stream)
{
    const float* x  = (const float*)d_in[0];
    const float* Wq = (const float*)d_in[1];
    const float* bq = (const float*)d_in[2];
    const float* Wk = (const float*)d_in[3];
    const float* bk = (const float*)d_in[4];
    const float* Wv = (const float*)d_in[5];
    const float* bv = (const float*)d_in[6];
    const float* Wo = (const float*)d_in[7];
    const float* bo = (const float*)d_in[8];

    short* xb  = (short*)d_ws;                   // bf16 [4096,1024]
    short* Tq  = xb  + (size_t)M_ * E_;          // bf16 Wq^T [n][k]; Tq|Tk|Tv fused
    short* Tk  = Tq  + (size_t)E_ * E_;
    short* Tv  = Tk  + (size_t)E_ * E_;
    short* To  = Tv  + (size_t)E_ * E_;
    short* Qw  = To  + (size_t)E_ * E_;          // bf16 [B,H,S,D] (exp2-scaled)
    short* Kw  = Qw  + (size_t)M_ * E_;          // bf16 tiled-swizzled K
    short* Vw  = Kw  + (size_t)M_ * E_;          // bf16 tiled-swizzled V
    short* AOw = Vw  + (size_t)M_ * E_;          // bf16 [B,S,H,D]

    dim3 blk(256);
    prep<<<dim3(2048 + 4096), blk, 0, stream>>>(x, xb, Wq, Wk, Wv, Wo, Tq, Tk, Tv, To);
    qkv_gemm<<<dim3(256), dim3(512), 0, stream>>>(xb, Tq, bq, bk, bv, Qw, Kw, Vw);
    attn_kernel<<<dim3(B_*H_, S_/64), blk, 0, stream>>>(Qw, Kw, Vw, AOw);
    out_gemm<<<dim3(512), blk, 0, stream>>>(AOw, To, bo, (float*)d_out);
}